// Round 4
// baseline (146.529 us; speedup 1.0000x reference)
//
#include <hip/hip_runtime.h>
#include <hip/hip_bf16.h>

// CoreAttention B=2 S=2048 H=16 D=64, f32 in/out, causal. Flash-attn fwd,
// bf16 MFMA 16x16x32. R4: 8-wave blocks = two concurrent 4-wave groups on
// paired Q-tiles (i, 31-i) sharing K/V staging; HW cvt_pk bf16 conversion;
// defer-max (THR=8) online softmax; tr-native subtiled V/P^T; 1 barrier/tile.

typedef __attribute__((ext_vector_type(8))) short short8;
typedef __attribute__((ext_vector_type(4))) short short4v;
typedef __attribute__((ext_vector_type(4))) float f32x4;

__device__ __forceinline__ unsigned cvtpk(float a, float b) {
    __hip_bfloat162 h = __float22bfloat162_rn(make_float2(a, b));
    union { __hip_bfloat162 h; unsigned u; } c; c.h = h;
    return c.u;
}

__device__ __forceinline__ short8 pack8(float4 a, float4 b) {
    union { short8 s; unsigned u[4]; } w;
    w.u[0] = cvtpk(a.x, a.y); w.u[1] = cvtpk(a.z, a.w);
    w.u[2] = cvtpk(b.x, b.y); w.u[3] = cvtpk(b.z, b.w);
    return w.s;
}

#define TR64(dst, addr) \
    asm volatile("ds_read_b64_tr_b16 %0, %1" : "=v"(dst) : "v"(addr))

__global__ __launch_bounds__(512, 4)
void CoreAttention_68710886801875_kernel(const float* __restrict__ Q,
                                         const float* __restrict__ K,
                                         const float* __restrict__ V,
                                         float* __restrict__ O)
{
    constexpr int S = 2048, HD = 1024;
    constexpr float SCALE = 0.125f * 1.44269504088896340736f;  // 1/sqrt(64)*log2(e)

    __shared__ __align__(16) unsigned short ldsK[2][64 * 64];  // [k][d] XOR-swizzled rows
    __shared__ __align__(16) unsigned short ldsV[2][64 * 64];  // [k/4][d/16][4][16] subtiled
    __shared__ __align__(16) unsigned short ldsPT[8][64 * 16]; // per-wave [k/4][4][16] subtiled

    const int tid = threadIdx.x;
    const int wid = tid >> 6, lane = tid & 63, g = lane >> 4, lm = lane & 15;
    const int grp = wid >> 2, w4 = wid & 3;

    // grid 512: b(1b) | h(4b) | i(4b); blocks bx and bx+256 share a CU (round-
    // robin) and get complementary i -> complementary spans.
    const int bx = blockIdx.x;
    const int i_raw = bx & 15;
    const int h = (bx >> 4) & 15;
    const int b = (bx >> 8) & 1;
    const int i = b ? (15 - i_raw) : i_raw;
    const int myQt = grp ? (31 - i) : i;      // group A: short tile, B: long tile
    const int myNt = myQt + 1;
    const int ntMax = 32 - i;                 // group B's count (always the max)
    const int q0 = myQt * 64;
    const size_t base = ((size_t)b * S) * HD + (size_t)h * 64;

    // ---- staging geometry: one row per thread (512 thr / 64 rows x 8 cols)
    const int r0 = tid >> 3, c8 = tid & 7;
    const float* kp0 = K + base + (size_t)r0 * HD + c8 * 8;
    const float* vp0 = V + base + (size_t)r0 * HD + c8 * 8;
    float4 kst0, kst1, vst0, vst1;

    auto ISSUE = [&](int k0) {
        const float* kp = kp0 + (size_t)k0 * HD;
        const float* vp = vp0 + (size_t)k0 * HD;
        kst0 = *(const float4*)kp; kst1 = *(const float4*)(kp + 4);
        vst0 = *(const float4*)vp; vst1 = *(const float4*)(vp + 4);
    };
    auto WRITE = [&](int buf) {
        const unsigned byteK = (unsigned)((r0 * 128 + c8 * 16) ^ ((r0 & 7) << 4));
        *(short8*)((char*)&ldsK[buf][0] + byteK) = pack8(kst0, kst1);
        const unsigned byteV = (unsigned)(((r0 >> 2) * 4 + (c8 >> 1)) * 128 +
                                          (r0 & 3) * 32 + (c8 & 1) * 16);
        *(short8*)((char*)&ldsV[buf][0] + byteV) = pack8(vst0, vst1);
    };

    // ---- Q fragments (A-layout: row=lm, k=g*8+j), scale*log2e folded
    short8 qf[2];
    {
        const float* qp = Q + base + (size_t)(q0 + w4 * 16 + lm) * HD + g * 8;
#pragma unroll
        for (int ks = 0; ks < 2; ++ks) {
            float4 a = *(const float4*)(qp + ks * 32);
            float4 c = *(const float4*)(qp + ks * 32 + 4);
            a.x *= SCALE; a.y *= SCALE; a.z *= SCALE; a.w *= SCALE;
            c.x *= SCALE; c.y *= SCALE; c.z *= SCALE; c.w *= SCALE;
            qf[ks] = pack8(a, c);
        }
    }

    f32x4 oacc[4];
#pragma unroll
    for (int n = 0; n < 4; ++n) oacc[n] = (f32x4){0.f, 0.f, 0.f, 0.f};
    float m_run[4], l_run[4];
#pragma unroll
    for (int r = 0; r < 4; ++r) { m_run[r] = -1e30f; l_run[r] = 0.f; }

    const unsigned vBase = (unsigned)(size_t)&ldsV[0][0];
    const unsigned pBase = (unsigned)(size_t)&ldsPT[wid][0];

    ISSUE(0);
    WRITE(0);
    __syncthreads();

    for (int t = 0; t < ntMax; ++t) {
        const int cur = t & 1;
        if (t + 1 < ntMax) ISSUE((t + 1) * 64);

        if (t < myNt) {
            const bool diag = (t == myNt - 1);
            const int nmax = diag ? w4 : 3;

            // ---- S' = Q K^T (log2-domain)
            f32x4 sv[4];
            __builtin_amdgcn_s_setprio(1);
#pragma unroll
            for (int n = 0; n < 4; ++n) {
                f32x4 acc = (f32x4){0.f, 0.f, 0.f, 0.f};
                if (n <= nmax) {
#pragma unroll
                    for (int ks = 0; ks < 2; ++ks) {
                        const int kr = n * 16 + lm;
                        const unsigned byte = cur * 8192u +
                            (unsigned)((kr * 128 + ks * 64 + g * 16) ^ ((kr & 7) << 4));
                        short8 kf = *(const short8*)((const char*)&ldsK[0][0] + byte);
                        acc = __builtin_amdgcn_mfma_f32_16x16x32_bf16(qf[ks], kf, acc, 0, 0, 0);
                    }
                    if (diag && n == w4) {
#pragma unroll
                        for (int r = 0; r < 4; ++r)
                            if (lm > g * 4 + r) acc[r] = -1e30f;
                    }
                } else {
                    acc = (f32x4){-1e30f, -1e30f, -1e30f, -1e30f};
                }
                sv[n] = acc;
            }
            __builtin_amdgcn_s_setprio(0);

            // ---- online softmax with defer-max (THR=8 in log2 domain)
            float mx[4];
#pragma unroll
            for (int r = 0; r < 4; ++r) {
                float m = fmaxf(fmaxf(sv[0][r], sv[1][r]), fmaxf(sv[2][r], sv[3][r]));
#pragma unroll
                for (int msk = 1; msk <= 8; msk <<= 1)
                    m = fmaxf(m, __shfl_xor(m, msk, 64));
                mx[r] = m;
            }
            bool need = false;
#pragma unroll
            for (int r = 0; r < 4; ++r) need |= (mx[r] > m_run[r] + 8.f);
            if (need) {
#pragma unroll
                for (int r = 0; r < 4; ++r) {
                    const float mn = fmaxf(m_run[r], mx[r]);
                    const float corr = exp2f(m_run[r] - mn);
                    m_run[r] = mn;
                    l_run[r] *= corr;
#pragma unroll
                    for (int n = 0; n < 4; ++n) oacc[n][r] *= corr;
                }
            }

            // ---- P = exp2(S'-m); packed P^T writes into tr-native subtiles
            float rsum[4] = {0.f, 0.f, 0.f, 0.f};
#pragma unroll
            for (int n = 0; n < 4; ++n) {
                float p[4];
#pragma unroll
                for (int r = 0; r < 4; ++r) {
                    p[r] = exp2f(sv[n][r] - m_run[r]);
                    rsum[r] += p[r];
                }
                union { short4v s; unsigned u[2]; } pk;
                pk.u[0] = cvtpk(p[0], p[1]);
                pk.u[1] = cvtpk(p[2], p[3]);
                const unsigned byte = (unsigned)((n * 4 + (lm >> 2)) * 128 +
                                                 (lm & 3) * 32 + g * 8);
                *(short4v*)((char*)&ldsPT[wid][0] + byte) = pk.s;
            }

#pragma unroll
            for (int r = 0; r < 4; ++r) {
                float s = rsum[r];
#pragma unroll
                for (int msk = 1; msk <= 8; msk <<= 1)
                    s += __shfl_xor(s, msk, 64);
                l_run[r] += s;
            }

            // ---- O += P V via tr reads
            asm volatile("s_waitcnt lgkmcnt(0)" ::: "memory");  // P^T visible
            short4v plo[2], phi[2], vlo[2][4], vhi[2][4];
#pragma unroll
            for (int ks = 0; ks < 2; ++ks) {
                const int k0b = ks * 32 + g * 8;
                const unsigned psub = (unsigned)((k0b >> 2) * 128 + lm * 8);
                TR64(plo[ks], pBase + psub);
                TR64(phi[ks], pBase + psub + 128);
                const unsigned vb = vBase + cur * 8192u;
#pragma unroll
                for (int n = 0; n < 4; ++n) {
                    const unsigned vsub = (unsigned)(((k0b >> 2) * 4 + n) * 128 + lm * 8);
                    TR64(vlo[ks][n], vb + vsub);
                    TR64(vhi[ks][n], vb + vsub + 512);
                }
            }
            asm volatile("s_waitcnt lgkmcnt(0)" ::: "memory");
            __builtin_amdgcn_sched_barrier(0);
            __builtin_amdgcn_s_setprio(1);
#pragma unroll
            for (int ks = 0; ks < 2; ++ks) {
                const short8 pf = __builtin_shufflevector(plo[ks], phi[ks],
                                                          0, 1, 2, 3, 4, 5, 6, 7);
#pragma unroll
                for (int n = 0; n < 4; ++n) {
                    const short8 vf = __builtin_shufflevector(vlo[ks][n], vhi[ks][n],
                                                              0, 1, 2, 3, 4, 5, 6, 7);
                    oacc[n] = __builtin_amdgcn_mfma_f32_16x16x32_bf16(pf, vf, oacc[n], 0, 0, 0);
                }
            }
            __builtin_amdgcn_s_setprio(0);

            // ---- epilogue on this group's last tile
            if (diag) {
#pragma unroll
                for (int r = 0; r < 4; ++r) {
                    const int qrow = q0 + w4 * 16 + g * 4 + r;
                    const float inv = 1.0f / l_run[r];
                    float* op = O + base + (size_t)qrow * HD;
#pragma unroll
                    for (int n = 0; n < 4; ++n)
                        op[n * 16 + lm] = oacc[n][r] * inv;
                }
            }
        }

        if (t + 1 < ntMax) WRITE(cur ^ 1);
        __syncthreads();
    }
}

extern "C" void kernel_launch(void* const* d_in, const int* in_sizes, int n_in,
                              void* d_out, int out_size, void* d_ws, size_t ws_size,
                              hipStream_t stream) {
    (void)in_sizes; (void)n_in; (void)out_size; (void)d_ws; (void)ws_size;
    const float* Q = (const float*)d_in[0];
    const float* K = (const float*)d_in[1];
    const float* V = (const float*)d_in[2];
    float* O = (float*)d_out;

    dim3 grid(512);    // b * h * pair-index; 2 Q-tiles per block
    dim3 block(512);   // 8 waves: two 4-wave groups
    hipLaunchKernelGGL(CoreAttention_68710886801875_kernel, grid, block, 0, stream,
                       Q, K, V, O);
}

// Round 6
// 74.289 us; speedup vs baseline: 1.9724x; 1.9724x over previous
//
#include <hip/hip_runtime.h>
#include <hip/hip_bf16.h>

// CoreAttention B=2 S=2048 H=16 D=64, f32 in/out, causal. Flash-attn fwd,
// bf16 MFMA 16x16x32. R6 = R5 with the K-fragment swizzle-address bug fixed
// (XOR must apply to full column offset incl. g*16/ks*64 bits; add != xor).
// 4 waves x 32 Q-rows (QBLK=128), K/V frags register-reused across row-blocks,
// lazy per-lane l, defer-max (THR=8 log2), HW cvt_pk, XCD-chunked swizzle.

typedef __attribute__((ext_vector_type(8))) short short8;
typedef __attribute__((ext_vector_type(4))) short short4v;
typedef __attribute__((ext_vector_type(4))) float f32x4;

__device__ __forceinline__ unsigned cvtpk(float a, float b) {
    __hip_bfloat162 h = __float22bfloat162_rn(make_float2(a, b));
    union { __hip_bfloat162 h; unsigned u; } c; c.h = h;
    return c.u;
}

__device__ __forceinline__ short8 pack8(float4 a, float4 b) {
    union { short8 s; unsigned u[4]; } w;
    w.u[0] = cvtpk(a.x, a.y); w.u[1] = cvtpk(a.z, a.w);
    w.u[2] = cvtpk(b.x, b.y); w.u[3] = cvtpk(b.z, b.w);
    return w.s;
}

#define TR64(dst, addr) \
    asm volatile("ds_read_b64_tr_b16 %0, %1" : "=v"(dst) : "v"(addr))

__global__ __launch_bounds__(256, 2)
void CoreAttention_68710886801875_kernel(const float* __restrict__ Q,
                                         const float* __restrict__ K,
                                         const float* __restrict__ V,
                                         float* __restrict__ O)
{
    constexpr int S = 2048, HD = 1024;
    constexpr float SCALE = 0.125f * 1.44269504088896340736f;  // 1/sqrt(64)*log2(e)

    __shared__ __align__(16) unsigned short ldsK[2][64 * 64];     // [k][d] XOR-swizzled
    __shared__ __align__(16) unsigned short ldsV[2][64 * 64];     // [k/4][d/16][4][16]
    __shared__ __align__(16) unsigned short ldsPT[4][2][64 * 16]; // per-(wave,m) subtiled

    const int tid = threadIdx.x;
    const int wid = tid >> 6, lane = tid & 63, g = lane >> 4, lm = lane & 15;

    // 512 blocks: XCD-chunked (64 consecutive wg per XCD -> 4 heads, 4MB = L2);
    // complementary qt for wg and wg^32 so co-resident blocks balance.
    const int bx = blockIdx.x;
    const int wg = ((bx & 7) << 6) | (bx >> 3);
    const int j  = wg & 15;
    const int h  = (wg >> 4) & 15;
    const int b  = wg >> 8;
    const int qt = ((wg >> 5) & 1) ? j : (15 - j);
    const int q0 = qt * 128;
    const int nt = 2 * qt + 2;
    const int diagT = 2 * qt + (wid >> 1);   // this wave's diagonal KV-tile
    const int nd = (wid & 1) << 1;           // diag n-subtile for m=0 (m=1 -> nd+1)
    const size_t base = ((size_t)b * S) * HD + (size_t)h * 64;

    // ---- staging geometry: rows {r0, r0+32}, cols c8*8..c8*8+7
    const int r0 = tid >> 3, c8 = tid & 7;
    const float* kp0 = K + base + (size_t)r0 * HD + c8 * 8;
    const float* vp0 = V + base + (size_t)r0 * HD + c8 * 8;
    float4 kst[4], vst[4];

    auto ISSUE = [&](int k0) {
        const float* kp = kp0 + (size_t)k0 * HD;
        const float* vp = vp0 + (size_t)k0 * HD;
        kst[0] = *(const float4*)kp;
        kst[1] = *(const float4*)(kp + 4);
        kst[2] = *(const float4*)(kp + (size_t)32 * HD);
        kst[3] = *(const float4*)(kp + (size_t)32 * HD + 4);
        vst[0] = *(const float4*)vp;
        vst[1] = *(const float4*)(vp + 4);
        vst[2] = *(const float4*)(vp + (size_t)32 * HD);
        vst[3] = *(const float4*)(vp + (size_t)32 * HD + 4);
    };
    auto WRITE = [&](int buf) {
#pragma unroll
        for (int it = 0; it < 2; ++it) {
            const int r = r0 + it * 32;
            const unsigned byteK = (unsigned)((r * 128 + c8 * 16) ^ ((r & 7) << 4));
            *(short8*)((char*)&ldsK[buf][0] + byteK) = pack8(kst[it * 2], kst[it * 2 + 1]);
            const unsigned byteV = (unsigned)(((r >> 2) * 4 + (c8 >> 1)) * 128 +
                                              (r & 3) * 32 + (c8 & 1) * 16);
            *(short8*)((char*)&ldsV[buf][0] + byteV) = pack8(vst[it * 2], vst[it * 2 + 1]);
        }
    };

    // ---- Q fragments: 2 row-blocks x 2 k-halves (row = q0+wid*32+m*16+lm)
    short8 qf[2][2];
#pragma unroll
    for (int m = 0; m < 2; ++m) {
        const float* qp = Q + base + (size_t)(q0 + wid * 32 + m * 16 + lm) * HD + g * 8;
#pragma unroll
        for (int ks = 0; ks < 2; ++ks) {
            float4 a = *(const float4*)(qp + ks * 32);
            float4 c = *(const float4*)(qp + ks * 32 + 4);
            a.x *= SCALE; a.y *= SCALE; a.z *= SCALE; a.w *= SCALE;
            c.x *= SCALE; c.y *= SCALE; c.z *= SCALE; c.w *= SCALE;
            qf[m][ks] = pack8(a, c);
        }
    }

    f32x4 oacc[2][4];
#pragma unroll
    for (int m = 0; m < 2; ++m)
#pragma unroll
        for (int n = 0; n < 4; ++n) oacc[m][n] = (f32x4){0.f, 0.f, 0.f, 0.f};
    float m_run[2][4], l_run[2][4];
#pragma unroll
    for (int m = 0; m < 2; ++m)
#pragma unroll
        for (int r = 0; r < 4; ++r) { m_run[m][r] = -1e30f; l_run[m][r] = 0.f; }

    const unsigned vBase = (unsigned)(size_t)&ldsV[0][0];
    const unsigned pBase = (unsigned)(size_t)&ldsPT[wid][0][0];

    ISSUE(0);
    WRITE(0);
    __syncthreads();

    for (int t = 0; t < nt; ++t) {
        const int cur = t & 1;
        if (t + 1 < nt) ISSUE((t + 1) * 64);

        if (t <= diagT) {
            const bool full = (t < diagT);

            // ---- S' = Q K^T (log2 domain); K-frags register-shared across m
            f32x4 sv[2][4];
            __builtin_amdgcn_s_setprio(1);
#pragma unroll
            for (int n = 0; n < 4; ++n) {
                short8 kf0, kf1;
                if (full || n <= nd + 1) {
                    const int kr = n * 16 + lm;
                    // swizzle XOR must cover the FULL column offset (bits 4-6)
                    const unsigned b0 = cur * 8192u +
                        (unsigned)((kr * 128 + g * 16) ^ ((kr & 7) << 4));
                    const unsigned b1 = cur * 8192u +
                        (unsigned)((kr * 128 + 64 + g * 16) ^ ((kr & 7) << 4));
                    kf0 = *(const short8*)((const char*)&ldsK[0][0] + b0);
                    kf1 = *(const short8*)((const char*)&ldsK[0][0] + b1);
                }
#pragma unroll
                for (int m = 0; m < 2; ++m) {
                    if (full || n <= nd + m) {
                        f32x4 acc = (f32x4){0.f, 0.f, 0.f, 0.f};
                        acc = __builtin_amdgcn_mfma_f32_16x16x32_bf16(qf[m][0], kf0, acc, 0, 0, 0);
                        acc = __builtin_amdgcn_mfma_f32_16x16x32_bf16(qf[m][1], kf1, acc, 0, 0, 0);
                        if (!full && n == nd + m) {
#pragma unroll
                            for (int r = 0; r < 4; ++r)
                                if (lm > g * 4 + r) acc[r] = -1e30f;
                        }
                        sv[m][n] = acc;
                    } else {
                        sv[m][n] = (f32x4){-1e30f, -1e30f, -1e30f, -1e30f};
                    }
                }
            }
            __builtin_amdgcn_s_setprio(0);

            // ---- defer-max: local max per (m,r); full reduce only if needed
            float lmax[2][4];
            int need = 0;
#pragma unroll
            for (int m = 0; m < 2; ++m)
#pragma unroll
                for (int r = 0; r < 4; ++r) {
                    lmax[m][r] = fmaxf(fmaxf(sv[m][0][r], sv[m][1][r]),
                                       fmaxf(sv[m][2][r], sv[m][3][r]));
                    need |= (lmax[m][r] > m_run[m][r] + 8.f) ? 1 : 0;
                }
            if (__any(need)) {
#pragma unroll
                for (int m = 0; m < 2; ++m)
#pragma unroll
                    for (int r = 0; r < 4; ++r) {
                        float mx = lmax[m][r];
#pragma unroll
                        for (int msk = 1; msk <= 8; msk <<= 1)
                            mx = fmaxf(mx, __shfl_xor(mx, msk, 64));
                        const float mn = fmaxf(m_run[m][r], mx);
                        const float corr = exp2f(m_run[m][r] - mn);
                        m_run[m][r] = mn;
                        l_run[m][r] *= corr;
#pragma unroll
                        for (int n = 0; n < 4; ++n) oacc[m][n][r] *= corr;
                    }
            }

            // ---- P = exp2(S'-m); per-lane l partials; packed P^T subtile writes
#pragma unroll
            for (int m = 0; m < 2; ++m)
#pragma unroll
                for (int n = 0; n < 4; ++n) {
                    float p[4];
#pragma unroll
                    for (int r = 0; r < 4; ++r) {
                        p[r] = exp2f(sv[m][n][r] - m_run[m][r]);
                        l_run[m][r] += p[r];
                    }
                    union { short4v s; unsigned u[2]; } pk;
                    pk.u[0] = cvtpk(p[0], p[1]);
                    pk.u[1] = cvtpk(p[2], p[3]);
                    const unsigned byte = (unsigned)((n * 4 + (lm >> 2)) * 128 +
                                                     (lm & 3) * 32 + g * 8);
                    *(short4v*)((char*)&ldsPT[wid][m][0] + byte) = pk.s;
                }

            // ---- O += P V via tr reads; V frags shared across m
            asm volatile("s_waitcnt lgkmcnt(0)" ::: "memory");
            short4v vlo[2][4], vhi[2][4], plo[2][2], phi[2][2];
#pragma unroll
            for (int ks = 0; ks < 2; ++ks) {
                const unsigned sub = (unsigned)(8 * ks + 2 * g);
#pragma unroll
                for (int n = 0; n < 4; ++n) {
                    const unsigned va = vBase + cur * 8192u + (sub * 4 + n) * 128 + lm * 8;
                    TR64(vlo[ks][n], va);
                    TR64(vhi[ks][n], va + 512);
                }
#pragma unroll
                for (int m = 0; m < 2; ++m) {
                    const unsigned pa = pBase + m * 2048u + sub * 128 + lm * 8;
                    TR64(plo[m][ks], pa);
                    TR64(phi[m][ks], pa + 128);
                }
            }
            asm volatile("s_waitcnt lgkmcnt(0)" ::: "memory");
            __builtin_amdgcn_sched_barrier(0);
            __builtin_amdgcn_s_setprio(1);
#pragma unroll
            for (int m = 0; m < 2; ++m)
#pragma unroll
                for (int ks = 0; ks < 2; ++ks) {
                    const short8 pf = __builtin_shufflevector(plo[m][ks], phi[m][ks],
                                                              0, 1, 2, 3, 4, 5, 6, 7);
#pragma unroll
                    for (int n = 0; n < 4; ++n) {
                        const short8 vf = __builtin_shufflevector(vlo[ks][n], vhi[ks][n],
                                                                  0, 1, 2, 3, 4, 5, 6, 7);
                        oacc[m][n] = __builtin_amdgcn_mfma_f32_16x16x32_bf16(pf, vf,
                                                                             oacc[m][n], 0, 0, 0);
                    }
                }
            __builtin_amdgcn_s_setprio(0);
        }

        if (t + 1 < nt) WRITE(cur ^ 1);
        __syncthreads();
    }

    // ---- epilogue: reduce per-lane l partials across the 16 lm-lanes, store
#pragma unroll
    for (int m = 0; m < 2; ++m)
#pragma unroll
        for (int r = 0; r < 4; ++r) {
            float l = l_run[m][r];
#pragma unroll
            for (int msk = 1; msk <= 8; msk <<= 1)
                l += __shfl_xor(l, msk, 64);
            const float inv = 1.0f / l;
            const int row = q0 + wid * 32 + m * 16 + g * 4 + r;
            float* op = O + base + (size_t)row * HD;
#pragma unroll
            for (int n = 0; n < 4; ++n)
                op[n * 16 + lm] = oacc[m][n][r] * inv;
        }
}

extern "C" void kernel_launch(void* const* d_in, const int* in_sizes, int n_in,
                              void* d_out, int out_size, void* d_ws, size_t ws_size,
                              hipStream_t stream) {
    (void)in_sizes; (void)n_in; (void)out_size; (void)d_ws; (void)ws_size;
    const float* Q = (const float*)d_in[0];
    const float* K = (const float*)d_in[1];
    const float* V = (const float*)d_in[2];
    float* O = (float*)d_out;

    dim3 grid(512);    // B * H * (S/128) Q-tiles, one per block
    dim3 block(256);   // 4 waves x 32 Q-rows
    hipLaunchKernelGGL(CoreAttention_68710886801875_kernel, grid, block, 0, stream,
                       Q, K, V, O);
}